// Round 1
// 223.359 us; speedup vs baseline: 1.0207x; 1.0207x over previous
//
#include <hip/hip_runtime.h>
#include <math.h>

// Problem constants: IN_DIM=128, HEADS=8, HEAD_DIM=16, HEADS*HEAD_DIM=128.
#define DIM 128
#define N_HEADS 8
#define HD 16
#define CAP 96   // fixed bucket capacity (degrees ~Poisson(16); P(>96)~1e-40)

typedef __attribute__((ext_vector_type(8))) short bf16x8;   // MFMA A/B frag (4 VGPRs)
typedef __attribute__((ext_vector_type(4))) float f32x4;    // MFMA C/D frag

// ---------------------------------------------------------------------------
// bf16 helpers (RNE pack, cheap unpack)
// ---------------------------------------------------------------------------
__device__ __forceinline__ unsigned bf16pack2(float a, float b) {
    unsigned ua = __builtin_bit_cast(unsigned, a);
    unsigned ub = __builtin_bit_cast(unsigned, b);
    ua = (ua + 0x7FFFu + ((ua >> 16) & 1u)) >> 16;
    ub = (ub + 0x7FFFu + ((ub >> 16) & 1u)) >> 16;
    return ua | (ub << 16);
}
__device__ __forceinline__ float bf16lo(unsigned p) {
    return __builtin_bit_cast(float, p << 16);
}
__device__ __forceinline__ float bf16hi(unsigned p) {
    return __builtin_bit_cast(float, p & 0xFFFF0000u);
}

// ---------------------------------------------------------------------------
// Init: zero cnt (blocks [0,NB)) || convert W -> WT/bias384 (blocks >= NB).
// WT[c][k] = bf16(W_m[k][c&127]) for c in [0,384).
// ---------------------------------------------------------------------------
__global__ __launch_bounds__(256)
void init_kernel(const float* __restrict__ WQ, const float* __restrict__ bQ,
                 const float* __restrict__ WK, const float* __restrict__ bK,
                 const float* __restrict__ WV, const float* __restrict__ bV,
                 unsigned short* __restrict__ WT, float* __restrict__ bias384,
                 int* __restrict__ cnt, int NB, int N)
{
    if ((int)blockIdx.x < NB) {
        int i = blockIdx.x * 256 + threadIdx.x;
        if (i < N) cnt[i] = 0;
    } else {
        int idx = ((int)blockIdx.x - NB) * 256 + threadIdx.x;   // 0..49151
        int c = idx >> 7, k = idx & 127;
        const float* W; const float* b; int col = c & 127;
        if (c < 128)      { W = WQ; b = bQ; }
        else if (c < 256) { W = WK; b = bK; }
        else              { W = WV; b = bV; }
        float v = W[k * DIM + col];
        WT[(size_t)c * DIM + k] = (unsigned short)(bf16pack2(v, 0.0f) & 0xFFFFu);
        if (k == 0) bias384[c] = b[col];
    }
}

// ---------------------------------------------------------------------------
// Fused append + QKV-MFMA. The two phases are independent (append writes
// cnt/srcsF; qkv writes Qd/KVd) and use disjoint pipes (atomics/scatter vs
// MFMA/LDS) -> co-schedule them in one dispatch. qkv blocks come FIRST in
// dispatch order so the long MFMA blocks start immediately; the 3125 short
// append blocks flow in around them.
//
// qkv: A = WT (m = output col), B = h tile (n = node), 16x16x32 bf16 MFMA.
// D[m=col][n=node]: col = quad*4 + reg, node = lane&15.
// Qd layout (dwords; row n = 64 dwords = 256 B): dword j = Q dims 2j,2j+1.
// KV chunk layout (dwords; row n = 128 dwords = 512 B):
//   chunk c in [0,16): dwords [8c..8c+3] = K dims 8c..8c+7,
//                      dwords [8c+4..8c+7] = V dims 8c..8c+7.
// ---------------------------------------------------------------------------
__global__ __launch_bounds__(256)
void append_qkv_kernel(const int* __restrict__ src, const int* __restrict__ dst,
                       int* __restrict__ cnt, int* __restrict__ srcsF, int E, int QB,
                       const float* __restrict__ h,
                       const unsigned short* __restrict__ WT,
                       const float* __restrict__ bias384,
                       unsigned* __restrict__ Qd, unsigned* __restrict__ KVd,
                       int N)
{
    __shared__ unsigned short hs[64 * 136];

    if ((int)blockIdx.x >= QB) {
        // ---- append phase: fixed-capacity bucket append ------------------
        int e = ((int)blockIdx.x - QB) * 256 + threadIdx.x;
        if (e < E) {
            int d    = dst[e];
            int slot = atomicAdd(&cnt[d], 1);
            if (slot < CAP) srcsF[(size_t)d * CAP + slot] = src[e];
        }
        return;
    }

    // ---- qkv phase ------------------------------------------------------
    const int tid = threadIdx.x;
    const int n0  = blockIdx.x * 64;

    // stage 64x128 h tile as bf16
    #pragma unroll
    for (int i = 0; i < 4; ++i) {
        int lin  = i * 256 + tid;          // 0..1023
        int node = lin >> 4;               // 0..63
        int k0   = (lin & 15) * 8;         // 0..120
        int gn   = n0 + node;
        float4 a0, a1;
        if (gn < N) {
            a0 = *(const float4*)(h + (size_t)gn * DIM + k0);
            a1 = *(const float4*)(h + (size_t)gn * DIM + k0 + 4);
        } else {
            a0 = make_float4(0.f, 0.f, 0.f, 0.f);
            a1 = a0;
        }
        uint4 p = make_uint4(bf16pack2(a0.x, a0.y), bf16pack2(a0.z, a0.w),
                             bf16pack2(a1.x, a1.y), bf16pack2(a1.z, a1.w));
        *(uint4*)(hs + node * 136 + k0) = p;
    }
    __syncthreads();

    const int wave   = tid >> 6;
    const int l      = tid & 63;
    const int lane16 = l & 15;
    const int quad   = l >> 4;
    const int wc0    = wave * 96;

    // acc[ct][rt]: cols (wc0+ct*16+quad*4 .. +3), node n0+rt*16+lane16
    f32x4 acc[6][4];
    #pragma unroll
    for (int ct = 0; ct < 6; ++ct) {
        float4 bv = *(const float4*)(bias384 + wc0 + ct * 16 + quad * 4);
        #pragma unroll
        for (int rt = 0; rt < 4; ++rt)
            acc[ct][rt] = (f32x4){bv.x, bv.y, bv.z, bv.w};
    }

    #pragma unroll
    for (int ks = 0; ks < 4; ++ks) {
        bf16x8 a[6], b[4];
        #pragma unroll
        for (int ct = 0; ct < 6; ++ct)
            a[ct] = *(const bf16x8*)(WT + (size_t)(wc0 + ct * 16 + lane16) * DIM
                                         + ks * 32 + quad * 8);
        #pragma unroll
        for (int rt = 0; rt < 4; ++rt)
            b[rt] = *(const bf16x8*)(hs + (rt * 16 + lane16) * 136 + ks * 32 + quad * 8);
        #pragma unroll
        for (int ct = 0; ct < 6; ++ct)
            #pragma unroll
            for (int rt = 0; rt < 4; ++rt)
                acc[ct][rt] = __builtin_amdgcn_mfma_f32_16x16x32_bf16(
                    a[ct], b[rt], acc[ct][rt], 0, 0, 0);
    }

    // epilogue: uint2 stores (bf16 pairs everywhere)
    #pragma unroll
    for (int ct = 0; ct < 6; ++ct) {
        const int col = wc0 + ct * 16 + quad * 4;   // multiple of 4
        #pragma unroll
        for (int rt = 0; rt < 4; ++rt) {
            int gn = n0 + rt * 16 + lane16;
            if (gn >= N) continue;
            f32x4 v = acc[ct][rt];
            uint2 pr = make_uint2(bf16pack2(v[0], v[1]), bf16pack2(v[2], v[3]));
            if (col < 128) {
                *(uint2*)(Qd + (size_t)gn * 64 + (col >> 1)) = pr;
            } else if (col < 256) {
                int c = col - 128;   // K dims c..c+3 -> chunk c>>3, pair (c&4)>>1
                *(uint2*)(KVd + (size_t)gn * 128 + ((c >> 3) * 8) + ((c & 4) >> 1)) = pr;
            } else {
                int c = col - 256;   // V dims -> same chunk, +4 dwords
                *(uint2*)(KVd + (size_t)gn * 128 + ((c >> 3) * 8) + 4 + ((c & 4) >> 1)) = pr;
            }
        }
    }
}

// ---------------------------------------------------------------------------
// Aggregate v2: persistent grid-stride waves + cross-node software pipeline.
//
// Diagnosis (round-0 counters): 0 MFMA, VALUBusy 47%, HBM 42%, Occupancy 33%
// -> latency-bound gather. Per node the chain was cnt -> (deg-dependent
// bucket address) -> bucket -> KV: ~3 serial round trips for ~16 edges.
// Fixes:
//   * wave processes ~N/8192 nodes (grid-stride); next node's deg, Qd row and
//     first 32 bucket indices are prefetched BEFORE processing the current
//     node, so the cnt/bucket round trips hide under the current node's work.
//   * gather address uses (val ? idx : 0) -- node 0 is always a safe in-range
//     row -- removing the deg-dependence from the KV address chain.
// Inner loop (16 lanes per edge, 4 edge slots) is the round-8-proven one.
// ---------------------------------------------------------------------------
__device__ __forceinline__ void agg_chunk16(
    const unsigned* __restrict__ KVd, int eg, int deg, int slot, int c,
    const int* raw,
    float q0, float q1, float q2, float q3,
    float q4, float q5, float q6, float q7,
    float acc[8], float& zs)
{
    bool val[4];
    const uint4* p[4];
    #pragma unroll
    for (int j = 0; j < 4; ++j) {
        int ee = eg + j * 4 + slot;
        val[j] = ee < deg;
        int s  = val[j] ? raw[j] : 0;
        p[j]   = (const uint4*)(KVd + (size_t)s * 128 + c * 8);
    }
    uint4 K[4], V[4];
    #pragma unroll
    for (int j = 0; j < 4; ++j) { K[j] = p[j][0]; V[j] = p[j][1]; }

    float d[4];
    #pragma unroll
    for (int j = 0; j < 4; ++j)
        d[j] = bf16lo(K[j].x) * q0 + bf16hi(K[j].x) * q1
             + bf16lo(K[j].y) * q2 + bf16hi(K[j].y) * q3
             + bf16lo(K[j].z) * q4 + bf16hi(K[j].z) * q5
             + bf16lo(K[j].w) * q6 + bf16hi(K[j].w) * q7;
    #pragma unroll
    for (int j = 0; j < 4; ++j) d[j] += __shfl_xor(d[j], 1);

    #pragma unroll
    for (int j = 0; j < 4; ++j) {
        float pc = fminf(fmaxf(d[j] * 0.25f, -5.0f), 5.0f);
        float w  = val[j] ? __expf(pc) : 0.0f;
        zs += w;
        acc[0] += w * bf16lo(V[j].x); acc[1] += w * bf16hi(V[j].x);
        acc[2] += w * bf16lo(V[j].y); acc[3] += w * bf16hi(V[j].y);
        acc[4] += w * bf16lo(V[j].z); acc[5] += w * bf16hi(V[j].z);
        acc[6] += w * bf16lo(V[j].w); acc[7] += w * bf16hi(V[j].w);
    }
}

__global__ __launch_bounds__(256, 4)
void aggregate_kernel(const int* __restrict__ cnt, const int* __restrict__ srcsF,
                      const unsigned* __restrict__ Qd, const unsigned* __restrict__ KVd,
                      float* __restrict__ out, int N)
{
    const int l      = threadIdx.x & 63;
    const int slot   = l >> 4;
    const int c      = l & 15;
    const int stride = gridDim.x * 4;

    int node = blockIdx.x * 4 + (threadIdx.x >> 6);
    if (node >= N) return;

    // prime the pipeline: current node's deg, Q row, first 32 bucket indices
    int   deg = cnt[node];
    uint4 qd  = *(const uint4*)(Qd + (size_t)node * 64 + c * 4);
    int   pb[8];
    {
        const int* b = srcsF + (size_t)node * CAP;
        #pragma unroll
        for (int j = 0; j < 8; ++j)
            pb[j] = b[((j >> 2) << 4) + ((j & 3) << 2) + slot];   // ee 0..31
    }

    for (;;) {
        const int  nnode   = node + stride;
        const bool hasNext = nnode < N;

        // ---- prefetch next node (independent loads, hide under compute) --
        int ndeg = 0; uint4 nqd = make_uint4(0u, 0u, 0u, 0u); int npb[8];
        #pragma unroll
        for (int j = 0; j < 8; ++j) npb[j] = 0;
        if (hasNext) {
            ndeg = cnt[nnode];
            nqd  = *(const uint4*)(Qd + (size_t)nnode * 64 + c * 4);
            const int* b = srcsF + (size_t)nnode * CAP;
            #pragma unroll
            for (int j = 0; j < 8; ++j)
                npb[j] = b[((j >> 2) << 4) + ((j & 3) << 2) + slot];
        }

        // ---- process current node ---------------------------------------
        int degc = deg > CAP ? CAP : deg;
        const float q0 = bf16lo(qd.x), q1 = bf16hi(qd.x);
        const float q2 = bf16lo(qd.y), q3 = bf16hi(qd.y);
        const float q4 = bf16lo(qd.z), q5 = bf16hi(qd.z);
        const float q6 = bf16lo(qd.w), q7 = bf16hi(qd.w);

        float acc[8] = {0.f, 0.f, 0.f, 0.f, 0.f, 0.f, 0.f, 0.f};
        float zs = 0.f;

        if (degc > 0)
            agg_chunk16(KVd, 0, degc, slot, c, pb,
                        q0, q1, q2, q3, q4, q5, q6, q7, acc, zs);
        if (degc > 16)
            agg_chunk16(KVd, 16, degc, slot, c, pb + 4,
                        q0, q1, q2, q3, q4, q5, q6, q7, acc, zs);
        for (int eg = 32; eg < degc; eg += 16) {       // rare tail (deg > 32)
            int raw[4];
            const int* b = srcsF + (size_t)node * CAP;
            #pragma unroll
            for (int j = 0; j < 4; ++j) {
                int ee = eg + j * 4 + slot;
                raw[j] = b[ee < degc ? ee : 0];
            }
            agg_chunk16(KVd, eg, degc, slot, c, raw,
                        q0, q1, q2, q3, q4, q5, q6, q7, acc, zs);
        }

        // ---- cross-slot reduce (slots live in lane bits 4-5) ------------
        #pragma unroll
        for (int j = 0; j < 8; ++j) {
            acc[j] += __shfl_xor(acc[j], 16);
            acc[j] += __shfl_xor(acc[j], 32);
        }
        zs += __shfl_xor(zs, 16);
        zs += __shfl_xor(zs, 32);

        if (slot == 0) {
            float inv = (zs > 0.0f) ? (1.0f / zs) : 0.0f;
            *(float4*)(out + (size_t)node * DIM + c * 8) =
                make_float4(acc[0] * inv, acc[1] * inv, acc[2] * inv, acc[3] * inv);
            *(float4*)(out + (size_t)node * DIM + c * 8 + 4) =
                make_float4(acc[4] * inv, acc[5] * inv, acc[6] * inv, acc[7] * inv);
        }

        if (!hasNext) break;
        node = nnode; deg = ndeg; qd = nqd;
        #pragma unroll
        for (int j = 0; j < 8; ++j) pb[j] = npb[j];
    }
}

// ---------------------------------------------------------------------------
extern "C" void kernel_launch(void* const* d_in, const int* in_sizes, int n_in,
                              void* d_out, int out_size, void* d_ws, size_t ws_size,
                              hipStream_t stream) {
    const float* h   = (const float*)d_in[0];
    const int*   src = (const int*)  d_in[1];
    const int*   dst = (const int*)  d_in[2];
    const float* WQ  = (const float*)d_in[3];
    const float* bQ  = (const float*)d_in[4];
    const float* WK  = (const float*)d_in[5];
    const float* bK  = (const float*)d_in[6];
    const float* WV  = (const float*)d_in[7];
    const float* bV  = (const float*)d_in[8];
    float* out = (float*)d_out;

    const int N  = in_sizes[0] / DIM;
    const int E  = in_sizes[1];
    const int NB = (N + 255) / 256;       // blocks to zero cnt
    const int EB = (E + 255) / 256;       // edge blocks
    const int QB = (N + 63) / 64;         // qkv blocks
    const int nConv = (384 * DIM) / 256;  // convert blocks

    // Workspace: Qd (12.8MB) | KVd (25.6MB) | WT (96KB) | bias384 | cnt (200KB)
    //            | srcsF (N*CAP*4 = 19.2MB)   -> ~58 MB total
    char* w = (char*)d_ws;
    unsigned*       Qd      = (unsigned*)w;        w += (size_t)N * 64  * sizeof(unsigned);
    unsigned*       KVd     = (unsigned*)w;        w += (size_t)N * 128 * sizeof(unsigned);
    unsigned short* WT      = (unsigned short*)w;  w += (size_t)384 * DIM * sizeof(unsigned short);
    float*          bias384 = (float*)w;           w += 384 * sizeof(float);
    int*            cnt     = (int*)w;             w += (size_t)N * sizeof(int);
    int*            srcsF   = (int*)w;

    init_kernel<<<NB + nConv, 256, 0, stream>>>(WQ, bQ, WK, bK, WV, bV,
                                                WT, bias384, cnt, NB, N);
    append_qkv_kernel<<<QB + EB, 256, 0, stream>>>(src, dst, cnt, srcsF, E, QB,
                                                   h, WT, bias384, Qd, KVd, N);
    aggregate_kernel<<<2048, 256, 0, stream>>>(cnt, srcsF, Qd, KVd, out, N);
}